// Round 10
// baseline (370.518 us; speedup 1.0000x reference)
//
#include <hip/hip_runtime.h>
#include <hip/hip_bf16.h>

#define B_   4
#define L_   1024
#define D_   1280
#define H_   20
#define DH_  64
#define BH_  (B_*H_)     // 80
#define L2_  (2*L_)      // 2048
#define ALPHA_ 0.48f
// Q prescale: 0.125 (score scale) * log2(e) -> scores in log2 domain, exp = v_exp_f32
#define QSCALE_ 0.180336880f

typedef __attribute__((ext_vector_type(8))) short short8;
typedef __attribute__((ext_vector_type(4))) float float4v;

__device__ __forceinline__ float exp2_fast(float x) {
    float r;
    asm volatile("v_exp_f32 %0, %1" : "=v"(r) : "v"(x));
    return r;
}

__device__ __forceinline__ ushort f2bf(float f) {
    union { float f; unsigned int i; } v; v.f = f;
    unsigned int i = v.i;
    unsigned int r = i + 0x7FFF + ((i >> 16) & 1);  // RNE
    return (ushort)(r >> 16);
}
__device__ __forceinline__ short8 pack8(float4 f0, float4 f1) {
    short8 o;
    o[0] = (short)f2bf(f0.x); o[1] = (short)f2bf(f0.y);
    o[2] = (short)f2bf(f0.z); o[3] = (short)f2bf(f0.w);
    o[4] = (short)f2bf(f1.x); o[5] = (short)f2bf(f1.y);
    o[6] = (short)f2bf(f1.z); o[7] = (short)f2bf(f1.w);
    return o;
}
// pack 4 f32 -> 4 bf16 (RNE) and store as one 8-byte write
__device__ __forceinline__ void pack4_store(ushort* dst, float a, float b, float c, float d) {
    union { __hip_bfloat162 h; unsigned int u; } x, y;
    x.h = __float22bfloat162_rn(make_float2(a, b));
    y.h = __float22bfloat162_rn(make_float2(c, d));
    uint2 v; v.x = x.u; v.y = y.u;
    *(uint2*)dst = v;
}

// async global->LDS, 16 B per lane; dest = wave-uniform base + lane*16
__device__ __forceinline__ void async16(const void* g, void* l) {
    __builtin_amdgcn_global_load_lds(
        (__attribute__((address_space(1))) void*)g,
        (__attribute__((address_space(3))) void*)l, 16, 0, 0);
}

// ---------------- fused prep (inputs are f32 — established R1/R2 evidence) ----------
// bi <  1600 : Wt[z][c][r] = bf16(w_z[r][c])          (weight transposes)
// bi <  2880 : Vt[bh][d][1024+kv] = bf16(ALPHA*Vbg[bh][kv][d])
// bi <  5440 : Xb  = bf16(X)
// bi <  8000 : Kcv = bf16(Kbg)
__global__ __launch_bounds__(256) void prep(
    const float* __restrict__ w0, const float* __restrict__ w1,
    const float* __restrict__ w2, const float* __restrict__ w3,
    ushort* __restrict__ Wt,
    const float* __restrict__ Vbg, ushort* __restrict__ Vt,
    const float* __restrict__ X, ushort* __restrict__ Xb,
    const float* __restrict__ Kbg, ushort* __restrict__ Kcv) {
    int bi = blockIdx.x, tid = threadIdx.x;
    if (bi < 2880) {
        bool doScale = (bi >= 1600);
        const float* src; ushort* dst; int srcld, dstld; long sbase, dbase;
        if (bi < 1600) {
            int z = bi / 400, t4 = bi % 400;
            int by = t4 / 20, bx = t4 % 20;
            const float* srcs[4] = {w0, w1, w2, w3};
            src = srcs[z]; srcld = D_; dstld = D_;
            sbase = (long)(by * 64) * D_ + bx * 64;
            dst = Wt + (long)z * D_ * D_;
            dbase = (long)(bx * 64) * D_ + by * 64;
        } else {
            int j = bi - 1600;          // 0..1279
            int bh = j >> 4, kt = j & 15;
            src = Vbg; srcld = DH_; dstld = L2_;
            sbase = ((long)bh * L_ + kt * 64) * DH_;
            dst = Vt;
            dbase = (long)bh * DH_ * L2_ + L_ + kt * 64;
        }
        __shared__ ushort t[64 * 72];
        int ldr = tid >> 3, ldc = (tid & 7) * 8;
#pragma unroll
        for (int i = 0; i < 2; i++) {
            int y = ldr + 32 * i;
            long idx = sbase + (long)y * srcld + ldc;
            float4 f0 = *(const float4*)&src[idx];
            float4 f1 = *(const float4*)&src[idx + 4];
            if (doScale) {
                f0.x *= ALPHA_; f0.y *= ALPHA_; f0.z *= ALPHA_; f0.w *= ALPHA_;
                f1.x *= ALPHA_; f1.y *= ALPHA_; f1.z *= ALPHA_; f1.w *= ALPHA_;
            }
            *(short8*)&t[y * 72 + ldc] = pack8(f0, f1);
        }
        __syncthreads();
        int c = tid & 63, r0 = (tid >> 6) * 16;
#pragma unroll
        for (int i = 0; i < 2; i++) {
            short8 o;
#pragma unroll
            for (int j2 = 0; j2 < 8; j2++) o[j2] = (short)t[(r0 + i * 8 + j2) * 72 + c];
            *(short8*)&dst[dbase + (long)c * dstld + r0 + i * 8] = o;
        }
    } else if (bi < 5440) {
        long i = ((long)(bi - 2880) * 256 + tid) * 8;
        *(short8*)&Xb[i] = pack8(*(const float4*)&X[i], *(const float4*)&X[i + 4]);
    } else {
        long i = ((long)(bi - 5440) * 256 + tid) * 8;
        *(short8*)&Kcv[i] = pack8(*(const float4*)&Kbg[i], *(const float4*)&Kbg[i + 4]);
    }
}

// ---------------- GEMM (bf16): C[m][n] = sum_k A[m][k]*Bt[n][k], K=1280 --------------
// Double-buffered async LDS staging, one barrier per K-iter.
// mode 0: scatter -> Qp (x QSCALE_), Kp, Vt (packed b64, transposed)
// mode 1: Out(f32) = acc + bo[n]
template<int BMt, int BNt, int WROWS, int WCOLS>
__global__ __launch_bounds__(256) void gemm_tpl(
    const ushort* __restrict__ A, const ushort* __restrict__ Bt,
    ushort* __restrict__ Qp, ushort* __restrict__ Kp, ushort* __restrict__ Vt,
    float* __restrict__ Out, const float* __restrict__ bo, int mode) {
    constexpr int MI = BMt / WROWS / 16;
    constexpr int NI = BNt / WCOLS / 16;
    constexpr int ASZ = BMt * 32, BSZ = BNt * 32;
    constexpr int RB = 1280 / BNt;  // blocks per 1280-wide output region
    __shared__ __align__(16) ushort Al[2 * ASZ];
    __shared__ __align__(16) ushort Bl[2 * BSZ];
    int tid = threadIdx.x;
    int bx = blockIdx.x, by = blockIdx.y;
    int w = tid >> 6, lane = tid & 63, l15 = lane & 15, quad = lane >> 4;
    int wm = (w / WCOLS) * (BMt / WROWS);
    int wn = (w % WCOLS) * (BNt / WCOLS);
    float4v acc[MI][NI] = {};
    const int K = 1280;
    constexpr int NK = 40;
    const ushort* Arow = A + (long)by * BMt * K + (tid >> 2) * K + (tid & 3) * 8;
    const ushort* Brow = Bt + (long)bx * BNt * K + (tid >> 2) * K + (tid & 3) * 8;

    auto stage = [&](int ki, int b) {
#pragma unroll
        for (int i = 0; i < BMt / 64; i++)
            async16(Arow + (long)i * 64 * K + ki * 32, &Al[b * ASZ + (i * 4 + w) * 512]);
#pragma unroll
        for (int i = 0; i < BNt / 64; i++)
            async16(Brow + (long)i * 64 * K + ki * 32, &Bl[b * BSZ + (i * 4 + w) * 512]);
    };

    stage(0, 0);
    __syncthreads();
    for (int ki = 0; ki < NK; ki++) {
        int cur = ki & 1;
        if (ki + 1 < NK) stage(ki + 1, 1 - cur);
        short8 av[MI], bv[NI];
#pragma unroll
        for (int mi = 0; mi < MI; mi++)
            av[mi] = *(const short8*)&Al[cur * ASZ + (wm + mi * 16 + l15) * 32 + quad * 8];
#pragma unroll
        for (int ni = 0; ni < NI; ni++)
            bv[ni] = *(const short8*)&Bl[cur * BSZ + (wn + ni * 16 + l15) * 32 + quad * 8];
#pragma unroll
        for (int mi = 0; mi < MI; mi++)
#pragma unroll
            for (int ni = 0; ni < NI; ni++)
                acc[mi][ni] = __builtin_amdgcn_mfma_f32_16x16x32_bf16(av[mi], bv[ni], acc[mi][ni], 0, 0, 0);
        __syncthreads();
    }

    if (mode == 0) {
        int which = bx / RB;
#pragma unroll
        for (int mi = 0; mi < MI; mi++) {
            int m0 = by * BMt + wm + mi * 16 + quad * 4;
            int b = m0 >> 10, l0 = m0 & 1023;
#pragma unroll
            for (int ni = 0; ni < NI; ni++) {
                int n = bx * BNt + wn + ni * 16 + l15;
                int np = n - which * 1280;
                int h = np >> 6, dh = np & 63;
                if (which == 0) {
#pragma unroll
                    for (int r = 0; r < 4; r++)
                        Qp[((long)(b * H_ + h) * L_ + l0 + r) * DH_ + dh] =
                            f2bf(acc[mi][ni][r] * QSCALE_);
                } else if (which == 1) {
#pragma unroll
                    for (int r = 0; r < 4; r++)
                        Kp[((long)(b * H_ + h) * L_ + l0 + r) * DH_ + dh] =
                            f2bf(acc[mi][ni][r]);
                } else {
                    pack4_store(&Vt[((long)(b * H_ + h) * DH_ + dh) * L2_ + l0],
                                acc[mi][ni][0], acc[mi][ni][1],
                                acc[mi][ni][2], acc[mi][ni][3]);
                }
            }
        }
    } else {
#pragma unroll
        for (int mi = 0; mi < MI; mi++) {
            int mloc = wm + mi * 16 + quad * 4;
#pragma unroll
            for (int ni = 0; ni < NI; ni++) {
                int nloc = wn + ni * 16 + l15;
#pragma unroll
                for (int r = 0; r < 4; r++) {
                    int m = by * BMt + mloc + r;
                    int n = bx * BNt + nloc;
                    Out[(long)m * D_ + n] = acc[mi][ni][r] + bo[n];
                }
            }
        }
    }
}

// ---------------- flash attention: 1-iter software pipeline (S(kt) + PV(kt-1)) ------
// Un-shifted softmax (scores bounded; exp fp32-safe) == reference softmax; scores in
// log2 domain (Qp pre-scaled), exp = raw v_exp_f32. alpha multiplies bg log2-scores
// (== alpha-scaling raw scores); V_bg pre-scaled by alpha in prep.
// S^T via MFMA(A=K,B=Q): lane q=l15 -> rs lane-local, P/Ctx stores packed.
// Pipeline: iter kt stages K(kt+1) & V(kt), computes S(kt) and PV(kt-1).
// PV(kt-1)'s MFMAs are independent of exp(kt)'s VALU -> scheduler interleaves them.
// P single-buffered: PV reads old P before exp overwrites (same-wave DS is in-order).
#define FS 72  // Pl row stride (elems): 144 B, 16B-aligned, 2-way banks only

__global__ __launch_bounds__(256) void flash_attn(
    const ushort* __restrict__ Qp, const ushort* __restrict__ Kp,
    const ushort* __restrict__ Kbg, const ushort* __restrict__ Vt,
    ushort* __restrict__ Ctx) {
    __shared__ __align__(16) ushort Kl[2 * 4096], Vl[2 * 4096];
    __shared__ __align__(16) ushort Pl[128 * FS];
    int tid = threadIdx.x;
    int w = tid >> 6, lane = tid & 63, l15 = lane & 15, quad = lane >> 4;
    int bi = blockIdx.x;
    int bh = (bi & 7) * 10 + ((bi >> 3) % 10);
    int qt = bi / 80;

    // Q fragments: direct global b128 loads (loop-invariant, one-time)
    short8 aq[2][2];
    const ushort* Qb = Qp + ((long)bh * L_ + qt * 128 + w * 32) * DH_;
#pragma unroll
    for (int mi = 0; mi < 2; mi++)
#pragma unroll
        for (int ks = 0; ks < 2; ks++)
            aq[mi][ks] = *(const short8*)&Qb[(mi * 16 + l15) * DH_ + ks * 32 + quad * 8];

    float rs[2] = {0.f, 0.f};
    float4v O[2][4] = {};
    const ushort* Vb = Vt + (long)bh * DH_ * L2_;
    int prow = (w * 32 + l15) * FS;  // wave-private Pl rows [w*32, w*32+32)

    auto stageK = [&](int kt) {  // K(kt) -> Kl[kt&1]
        const ushort* Ksrc = (kt < 16)
            ? Kp  + ((long)bh * L_ + kt * 64) * DH_
            : Kbg + ((long)bh * L_ + (kt - 16) * 64) * DH_;
#pragma unroll
        for (int i = 0; i < 2; i++) {
            int q = i * 4 + w;
            async16(&Ksrc[(long)lane * DH_ + q * 8], &Kl[(kt & 1) * 4096 + q * 512]);
        }
    };
    auto stageV = [&](int kt) {  // V(kt) -> Vl[kt&1] (consumed by PV in iter kt+1)
#pragma unroll
        for (int i = 0; i < 2; i++) {
            int q = i * 4 + w;
            async16(&Vb[(long)lane * L2_ + kt * 64 + q * 8], &Vl[(kt & 1) * 4096 + q * 512]);
        }
    };

    stageK(0);
    __syncthreads();
    for (int kt = 0; kt < 32; kt++) {
        int cur = kt & 1;
        if (kt + 1 < 32) stageK(kt + 1);
        stageV(kt);
        // S(kt): K frags from Kl[cur] (staged last iter, fenced by barrier)
        short8 bk[2][4];
#pragma unroll
        for (int ks = 0; ks < 2; ks++)
#pragma unroll
            for (int nt = 0; nt < 4; nt++)
                bk[ks][nt] = *(const short8*)&Kl[cur * 4096 + (ks * 4 + quad) * 512 + (nt * 16 + l15) * 8];
        float4v s[2][4] = {};
#pragma unroll
        for (int mi = 0; mi < 2; mi++)
#pragma unroll
            for (int ks = 0; ks < 2; ks++)
#pragma unroll
                for (int nt = 0; nt < 4; nt++)
                    s[mi][nt] = __builtin_amdgcn_mfma_f32_16x16x32_bf16(bk[ks][nt], aq[mi][ks], s[mi][nt], 0, 0, 0);
        // PV(kt-1): P from Pl (written last iter, barrier-fenced), V from Vl[1-cur]
        if (kt > 0) {
            short8 bv[2][4];
#pragma unroll
            for (int ks = 0; ks < 2; ks++)
#pragma unroll
                for (int nt = 0; nt < 4; nt++)
                    bv[ks][nt] = *(const short8*)&Vl[(1 - cur) * 4096 + (ks * 4 + quad) * 512 + (nt * 16 + l15) * 8];
#pragma unroll
            for (int mi = 0; mi < 2; mi++)
#pragma unroll
                for (int ks = 0; ks < 2; ks++) {
                    short8 ap = *(const short8*)&Pl[prow + mi * 16 * FS + ks * 32 + quad * 8];
#pragma unroll
                    for (int nt = 0; nt < 4; nt++)
                        O[mi][nt] = __builtin_amdgcn_mfma_f32_16x16x32_bf16(bv[ks][nt], ap, O[mi][nt], 0, 0, 0);
                }
        }
        // exp(kt) -> Pl (WAR vs PV's reads: same-wave DS ops are in-order; independent
        // of PV's MFMAs -> interleaved by the scheduler)
        bool bg = (kt >= 16);
#pragma unroll
        for (int mi = 0; mi < 2; mi++)
#pragma unroll
            for (int nt = 0; nt < 4; nt++) {
                float p[4];
#pragma unroll
                for (int r = 0; r < 4; r++) {
                    float sv = s[mi][nt][r];
                    if (bg) sv *= ALPHA_;
                    p[r] = exp2_fast(sv);
                    rs[mi] += p[r];
                }
                pack4_store(&Pl[prow + mi * 16 * FS + nt * 16 + quad * 4],
                            p[0], p[1], p[2], p[3]);
            }
        __syncthreads();  // staging drained; Pl(kt)/Vl visible for next iter
    }
    // epilogue: PV(31) — P(31) and V(31) written before the final barrier
    {
        short8 bv[2][4];
#pragma unroll
        for (int ks = 0; ks < 2; ks++)
#pragma unroll
            for (int nt = 0; nt < 4; nt++)
                bv[ks][nt] = *(const short8*)&Vl[4096 + (ks * 4 + quad) * 512 + (nt * 16 + l15) * 8];
        asm volatile("s_waitcnt lgkmcnt(0)" ::: "memory");
#pragma unroll
        for (int mi = 0; mi < 2; mi++)
#pragma unroll
            for (int ks = 0; ks < 2; ks++) {
                short8 ap = *(const short8*)&Pl[prow + mi * 16 * FS + ks * 32 + quad * 8];
#pragma unroll
                for (int nt = 0; nt < 4; nt++)
                    O[mi][nt] = __builtin_amdgcn_mfma_f32_16x16x32_bf16(bv[ks][nt], ap, O[mi][nt], 0, 0, 0);
            }
    }
    // rs partials live across the 4 quads of each q: reduce with 2 shuffles
    float rcp[2];
#pragma unroll
    for (int mi = 0; mi < 2; mi++) {
        float v = rs[mi];
        v += __shfl_xor(v, 16);
        v += __shfl_xor(v, 32);
        rcp[mi] = 1.f / v;
    }
    // Ctx[b*L+l][h*64+dh]: lane has l fixed (l15), dh = nt*16+quad*4+r -> packed 8B
    int b = bh / H_, h = bh % H_;
#pragma unroll
    for (int mi = 0; mi < 2; mi++) {
        long l = qt * 128 + w * 32 + mi * 16 + l15;
#pragma unroll
        for (int nt = 0; nt < 4; nt++)
            pack4_store(&Ctx[(long)(b * L_ + l) * D_ + h * DH_ + nt * 16 + quad * 4],
                        O[mi][nt][0] * rcp[mi], O[mi][nt][1] * rcp[mi],
                        O[mi][nt][2] * rcp[mi], O[mi][nt][3] * rcp[mi]);
    }
}

extern "C" void kernel_launch(void* const* d_in, const int* in_sizes, int n_in,
                              void* d_out, int out_size, void* d_ws, size_t ws_size,
                              hipStream_t stream) {
    const float* X   = (const float*)d_in[0];
    const float* Wq  = (const float*)d_in[1];
    const float* Wk  = (const float*)d_in[2];
    const float* Wv  = (const float*)d_in[3];
    const float* Wo  = (const float*)d_in[4];
    const float* bo  = (const float*)d_in[5];
    const float* Kbg = (const float*)d_in[6];
    const float* Vbg = (const float*)d_in[7];

    char* ws = (char*)d_ws;
    size_t off = 0;
    auto alloc = [&](size_t bytes) {
        void* p = ws + off;
        off = (off + bytes + 255) & ~(size_t)255;
        return p;
    };
    ushort* Wt    = (ushort*)alloc((size_t)4 * D_ * D_ * 2);     // Wq^T|Wk^T|Wv^T|Wo^T
    ushort* Qp    = (ushort*)alloc((size_t)BH_ * L_ * DH_ * 2);
    ushort* Kp    = (ushort*)alloc((size_t)BH_ * L_ * DH_ * 2);
    ushort* Kcv   = (ushort*)alloc((size_t)BH_ * L_ * DH_ * 2);  // bf16(Kbg)
    ushort* Vt    = (ushort*)alloc((size_t)BH_ * DH_ * L2_ * 2); // [V^T ; alpha V_bg^T]
    ushort* Xb    = (ushort*)alloc((size_t)B_ * L_ * D_ * 2);    // bf16(X); Ctx aliases
    ushort* Ctx   = Xb;  // Xb dead after QKV GEMM; flash writes Ctx afterwards
    ushort* Wqkv_t = Wt;
    ushort* Wo_t   = Wt + (size_t)3 * D_ * D_;

    dim3 tb(256);
    prep<<<8000, tb, 0, stream>>>(Wq, Wk, Wv, Wo, Wt, Vbg, Vt, X, Xb, Kbg, Kcv);
    // QKV projection: N = 3840 (Q|K|V), M = 4096 -> 1920 blocks
    gemm_tpl<128, 64, 2, 2><<<dim3(60, 32), tb, 0, stream>>>(
        Xb, Wqkv_t, Qp, Kp, Vt, nullptr, nullptr, 0);
    // attention: 640 blocks, XCD-swizzled, software-pipelined
    flash_attn<<<dim3(640), tb, 0, stream>>>(Qp, Kp, Kcv, Vt, Ctx);
    // output projection: 64x64 tiles -> 1280 blocks
    gemm_tpl<64, 64, 2, 2><<<dim3(20, 64), tb, 0, stream>>>(
        Ctx, Wo_t, nullptr, nullptr, nullptr, (float*)d_out, bo, 1);
}

// Round 11
// 314.440 us; speedup vs baseline: 1.1783x; 1.1783x over previous
//
#include <hip/hip_runtime.h>
#include <hip/hip_bf16.h>

#define B_   4
#define L_   1024
#define D_   1280
#define H_   20
#define DH_  64
#define BH_  (B_*H_)     // 80
#define L2_  (2*L_)      // 2048
#define ALPHA_ 0.48f
// Q prescale: 0.125 (score scale) * log2(e) -> scores in log2 domain, exp = v_exp_f32
#define QSCALE_ 0.180336880f

typedef __attribute__((ext_vector_type(8))) short short8;
typedef __attribute__((ext_vector_type(4))) float float4v;

__device__ __forceinline__ float exp2_fast(float x) {
    float r;
    asm volatile("v_exp_f32 %0, %1" : "=v"(r) : "v"(x));
    return r;
}

__device__ __forceinline__ ushort f2bf(float f) {
    union { float f; unsigned int i; } v; v.f = f;
    unsigned int i = v.i;
    unsigned int r = i + 0x7FFF + ((i >> 16) & 1);  // RNE
    return (ushort)(r >> 16);
}
__device__ __forceinline__ short8 pack8(float4 f0, float4 f1) {
    short8 o;
    o[0] = (short)f2bf(f0.x); o[1] = (short)f2bf(f0.y);
    o[2] = (short)f2bf(f0.z); o[3] = (short)f2bf(f0.w);
    o[4] = (short)f2bf(f1.x); o[5] = (short)f2bf(f1.y);
    o[6] = (short)f2bf(f1.z); o[7] = (short)f2bf(f1.w);
    return o;
}
// pack 4 f32 -> 4 bf16 (RNE) and store as one 8-byte write
__device__ __forceinline__ void pack4_store(ushort* dst, float a, float b, float c, float d) {
    union { __hip_bfloat162 h; unsigned int u; } x, y;
    x.h = __float22bfloat162_rn(make_float2(a, b));
    y.h = __float22bfloat162_rn(make_float2(c, d));
    uint2 v; v.x = x.u; v.y = y.u;
    *(uint2*)dst = v;
}

// async global->LDS, 16 B per lane; dest = wave-uniform base + lane*16
__device__ __forceinline__ void async16(const void* g, void* l) {
    __builtin_amdgcn_global_load_lds(
        (__attribute__((address_space(1))) void*)g,
        (__attribute__((address_space(3))) void*)l, 16, 0, 0);
}

// ---------------- fused prep (inputs f32) -------------------------------------------
// bi <  1600 : Wt[z][c][r] = bf16(w_z[r][c])          (weight transposes)
// bi <  2880 : Vt[bh][d][1024+kv] = bf16(ALPHA*Vbg[bh][kv][d])
// bi <  5440 : Xb  = bf16(X)
// bi <  8000 : Kcv = bf16(Kbg)
// Transpose write phase: lane -> (c = tid>>3 [+32], r-chunk = tid&7) so each wave
// writes 8 dst rows x 128 B contiguous (was 64 rows x 16 B: 4x write amplification).
__global__ __launch_bounds__(256) void prep(
    const float* __restrict__ w0, const float* __restrict__ w1,
    const float* __restrict__ w2, const float* __restrict__ w3,
    ushort* __restrict__ Wt,
    const float* __restrict__ Vbg, ushort* __restrict__ Vt,
    const float* __restrict__ X, ushort* __restrict__ Xb,
    const float* __restrict__ Kbg, ushort* __restrict__ Kcv) {
    int bi = blockIdx.x, tid = threadIdx.x;
    if (bi < 2880) {
        bool doScale = (bi >= 1600);
        const float* src; ushort* dst; int srcld, dstld; long sbase, dbase;
        if (bi < 1600) {
            int z = bi / 400, t4 = bi % 400;
            int by = t4 / 20, bx = t4 % 20;
            const float* srcs[4] = {w0, w1, w2, w3};
            src = srcs[z]; srcld = D_; dstld = D_;
            sbase = (long)(by * 64) * D_ + bx * 64;
            dst = Wt + (long)z * D_ * D_;
            dbase = (long)(bx * 64) * D_ + by * 64;
        } else {
            int j = bi - 1600;          // 0..1279
            int bh = j >> 4, kt = j & 15;
            src = Vbg; srcld = DH_; dstld = L2_;
            sbase = ((long)bh * L_ + kt * 64) * DH_;
            dst = Vt;
            dbase = (long)bh * DH_ * L2_ + L_ + kt * 64;
        }
        __shared__ ushort t[64 * 72];
        int ldr = tid >> 3, ldc = (tid & 7) * 8;
#pragma unroll
        for (int i = 0; i < 2; i++) {
            int y = ldr + 32 * i;
            long idx = sbase + (long)y * srcld + ldc;
            float4 f0 = *(const float4*)&src[idx];
            float4 f1 = *(const float4*)&src[idx + 4];
            if (doScale) {
                f0.x *= ALPHA_; f0.y *= ALPHA_; f0.z *= ALPHA_; f0.w *= ALPHA_;
                f1.x *= ALPHA_; f1.y *= ALPHA_; f1.z *= ALPHA_; f1.w *= ALPHA_;
            }
            *(short8*)&t[y * 72 + ldc] = pack8(f0, f1);
        }
        __syncthreads();
        int r8 = (tid & 7) * 8, c0 = tid >> 3;   // coalesced: wave covers 8 c-rows fully
#pragma unroll
        for (int i = 0; i < 2; i++) {
            int c = c0 + i * 32;
            short8 o;
#pragma unroll
            for (int j2 = 0; j2 < 8; j2++) o[j2] = (short)t[(r8 + j2) * 72 + c];
            *(short8*)&dst[dbase + (long)c * dstld + r8] = o;
        }
    } else if (bi < 5440) {
        long i = ((long)(bi - 2880) * 256 + tid) * 8;
        *(short8*)&Xb[i] = pack8(*(const float4*)&X[i], *(const float4*)&X[i + 4]);
    } else {
        long i = ((long)(bi - 5440) * 256 + tid) * 8;
        *(short8*)&Kcv[i] = pack8(*(const float4*)&Kbg[i], *(const float4*)&Kbg[i + 4]);
    }
}

// ---------------- GEMM (bf16): C[m][n] = sum_k A[m][k]*Bt[n][k], K=1280 --------------
// Double-buffered async LDS staging, one barrier per K-iter (R7 config).
// mode 0: scatter -> Qp (x QSCALE_), Kp, Vt (packed b64, transposed)
// mode 1: Out(f32) = acc + bo[n]
template<int BMt, int BNt, int WROWS, int WCOLS>
__global__ __launch_bounds__(256) void gemm_tpl(
    const ushort* __restrict__ A, const ushort* __restrict__ Bt,
    ushort* __restrict__ Qp, ushort* __restrict__ Kp, ushort* __restrict__ Vt,
    float* __restrict__ Out, const float* __restrict__ bo, int mode) {
    constexpr int MI = BMt / WROWS / 16;
    constexpr int NI = BNt / WCOLS / 16;
    constexpr int ASZ = BMt * 32, BSZ = BNt * 32;
    constexpr int RB = 1280 / BNt;  // blocks per 1280-wide output region
    __shared__ __align__(16) ushort Al[2 * ASZ];
    __shared__ __align__(16) ushort Bl[2 * BSZ];
    int tid = threadIdx.x;
    int bx = blockIdx.x, by = blockIdx.y;
    int w = tid >> 6, lane = tid & 63, l15 = lane & 15, quad = lane >> 4;
    int wm = (w / WCOLS) * (BMt / WROWS);
    int wn = (w % WCOLS) * (BNt / WCOLS);
    float4v acc[MI][NI] = {};
    const int K = 1280;
    constexpr int NK = 40;
    const ushort* Arow = A + (long)by * BMt * K + (tid >> 2) * K + (tid & 3) * 8;
    const ushort* Brow = Bt + (long)bx * BNt * K + (tid >> 2) * K + (tid & 3) * 8;

    auto stage = [&](int ki, int b) {
#pragma unroll
        for (int i = 0; i < BMt / 64; i++)
            async16(Arow + (long)i * 64 * K + ki * 32, &Al[b * ASZ + (i * 4 + w) * 512]);
#pragma unroll
        for (int i = 0; i < BNt / 64; i++)
            async16(Brow + (long)i * 64 * K + ki * 32, &Bl[b * BSZ + (i * 4 + w) * 512]);
    };

    stage(0, 0);
    __syncthreads();
    for (int ki = 0; ki < NK; ki++) {
        int cur = ki & 1;
        if (ki + 1 < NK) stage(ki + 1, 1 - cur);
        short8 av[MI], bv[NI];
#pragma unroll
        for (int mi = 0; mi < MI; mi++)
            av[mi] = *(const short8*)&Al[cur * ASZ + (wm + mi * 16 + l15) * 32 + quad * 8];
#pragma unroll
        for (int ni = 0; ni < NI; ni++)
            bv[ni] = *(const short8*)&Bl[cur * BSZ + (wn + ni * 16 + l15) * 32 + quad * 8];
#pragma unroll
        for (int mi = 0; mi < MI; mi++)
#pragma unroll
            for (int ni = 0; ni < NI; ni++)
                acc[mi][ni] = __builtin_amdgcn_mfma_f32_16x16x32_bf16(av[mi], bv[ni], acc[mi][ni], 0, 0, 0);
        __syncthreads();
    }

    if (mode == 0) {
        int which = bx / RB;
#pragma unroll
        for (int mi = 0; mi < MI; mi++) {
            int m0 = by * BMt + wm + mi * 16 + quad * 4;
            int b = m0 >> 10, l0 = m0 & 1023;
#pragma unroll
            for (int ni = 0; ni < NI; ni++) {
                int n = bx * BNt + wn + ni * 16 + l15;
                int np = n - which * 1280;
                int h = np >> 6, dh = np & 63;
                if (which == 0) {
#pragma unroll
                    for (int r = 0; r < 4; r++)
                        Qp[((long)(b * H_ + h) * L_ + l0 + r) * DH_ + dh] =
                            f2bf(acc[mi][ni][r] * QSCALE_);
                } else if (which == 1) {
#pragma unroll
                    for (int r = 0; r < 4; r++)
                        Kp[((long)(b * H_ + h) * L_ + l0 + r) * DH_ + dh] =
                            f2bf(acc[mi][ni][r]);
                } else {
                    pack4_store(&Vt[((long)(b * H_ + h) * DH_ + dh) * L2_ + l0],
                                acc[mi][ni][0], acc[mi][ni][1],
                                acc[mi][ni][2], acc[mi][ni][3]);
                }
            }
        }
    } else {
#pragma unroll
        for (int mi = 0; mi < MI; mi++) {
            int mloc = wm + mi * 16 + quad * 4;
#pragma unroll
            for (int ni = 0; ni < NI; ni++) {
                int nloc = wn + ni * 16 + l15;
#pragma unroll
                for (int r = 0; r < 4; r++) {
                    int m = by * BMt + mloc + r;
                    int n = bx * BNt + nloc;
                    Out[(long)m * D_ + n] = acc[mi][ni][r] + bo[n];
                }
            }
        }
    }
}

// ---------------- flash attention: 8 waves (512 thr), R7 staging, 1 barrier/kt -------
// Un-shifted softmax == reference (scores bounded, exp fp32-safe). Scores in log2
// domain (Qp x QSCALE_); exp = raw v_exp_f32; alpha multiplies bg log2-score
// (== alpha-scaling the raw score). V_bg pre-scaled by alpha in prep.
// S^T via MFMA(A=K,B=Q): lane q=l15 -> rs lane-local, P/Ctx stores packed.
// 8 waves each own 16 q rows: per-wave work halves vs R7, waves/SIMD doubles (3->6)
// for latency cover. Stage-together (K&V of kt+1 at iter top) preserves L2 timing.
#define FS 72  // Pl row stride (elems): 144 B, 16B-aligned, 2-way banks only

__global__ __launch_bounds__(512) void flash_attn(
    const ushort* __restrict__ Qp, const ushort* __restrict__ Kp,
    const ushort* __restrict__ Kbg, const ushort* __restrict__ Vt,
    ushort* __restrict__ Ctx) {
    __shared__ __align__(16) ushort Kl[2 * 4096], Vl[2 * 4096];
    __shared__ __align__(16) ushort Pl[128 * FS];
    int tid = threadIdx.x;
    int w = tid >> 6, lane = tid & 63, l15 = lane & 15, quad = lane >> 4;
    int bi = blockIdx.x;
    int bh = (bi & 7) * 10 + ((bi >> 3) % 10);
    int qt = bi / 80;

    // Q fragments: direct global b128 loads (loop-invariant; wave w owns q rows
    // qt*128 + w*16 .. +16)
    short8 aq[2];
    const ushort* Qb = Qp + ((long)bh * L_ + qt * 128 + w * 16) * DH_;
#pragma unroll
    for (int ks = 0; ks < 2; ks++)
        aq[ks] = *(const short8*)&Qb[l15 * DH_ + ks * 32 + quad * 8];

    float rs = 0.f;
    float4v O[4] = {};
    const ushort* Vb = Vt + (long)bh * DH_ * L2_;
    int prow = (w * 16 + l15) * FS;  // wave-private Pl rows [w*16, w*16+16)

    auto stage = [&](int kt, int b) {  // each of 8 waves stages 1 K-chunk + 1 V-chunk
        const ushort* Ksrc = (kt < 16)
            ? Kp  + ((long)bh * L_ + kt * 64) * DH_
            : Kbg + ((long)bh * L_ + (kt - 16) * 64) * DH_;
        async16(&Ksrc[(long)lane * DH_ + w * 8], &Kl[b * 4096 + w * 512]);
        async16(&Vb[(long)lane * L2_ + kt * 64 + w * 8], &Vl[b * 4096 + w * 512]);
    };

    stage(0, 0);
    __syncthreads();
    for (int kt = 0; kt < 32; kt++) {
        int cur = kt & 1;
        if (kt + 1 < 32) stage(kt + 1, 1 - cur);
        bool bg = (kt >= 16);
        // K fragments from LDS (chunk-major: [chunk][row][8])
        short8 bk[2][4];
#pragma unroll
        for (int ks = 0; ks < 2; ks++)
#pragma unroll
            for (int nt = 0; nt < 4; nt++)
                bk[ks][nt] = *(const short8*)&Kl[cur * 4096 + (ks * 4 + quad) * 512 + (nt * 16 + l15) * 8];
        // S^T = MFMA(A=K, B=Q): lane q = w*16+l15, kv = nt*16+quad*4+r
        float4v s[4] = {};
#pragma unroll
        for (int ks = 0; ks < 2; ks++)
#pragma unroll
            for (int nt = 0; nt < 4; nt++)
                s[nt] = __builtin_amdgcn_mfma_f32_16x16x32_bf16(bk[ks][nt], aq[ks], s[nt], 0, 0, 0);
        // p = 2^s (alpha on bg log2-scores); rs lane-local; P packed to wave-private LDS
#pragma unroll
        for (int nt = 0; nt < 4; nt++) {
            float p[4];
#pragma unroll
            for (int r = 0; r < 4; r++) {
                float sv = s[nt][r];
                if (bg) sv *= ALPHA_;
                p[r] = exp2_fast(sv);
                rs += p[r];
            }
            pack4_store(&Pl[prow + nt * 16 + quad * 4], p[0], p[1], p[2], p[3]);
        }
        // V fragments from LDS
        short8 bv[2][4];
#pragma unroll
        for (int ks = 0; ks < 2; ks++)
#pragma unroll
            for (int nt = 0; nt < 4; nt++)
                bv[ks][nt] = *(const short8*)&Vl[cur * 4096 + (ks * 4 + quad) * 512 + (nt * 16 + l15) * 8];
        // per-wave LDS write->read ordering for Pl (wave-private rows)
        asm volatile("s_waitcnt lgkmcnt(0)" ::: "memory");
        // O^T += MFMA(A=V^T, B=P): lane q = l15, d = nt*16+quad*4+r
#pragma unroll
        for (int ks = 0; ks < 2; ks++) {
            short8 ap = *(const short8*)&Pl[prow + ks * 32 + quad * 8];
#pragma unroll
            for (int nt = 0; nt < 4; nt++)
                O[nt] = __builtin_amdgcn_mfma_f32_16x16x32_bf16(bv[ks][nt], ap, O[nt], 0, 0, 0);
        }
        __syncthreads();  // prefetch complete + all waves done with cur buffer
    }
    // rs partials live across the 4 quads of each q: reduce with 2 shuffles
    float v = rs;
    v += __shfl_xor(v, 16);
    v += __shfl_xor(v, 32);
    float rcp = 1.f / v;
    // Ctx[b*L+l][h*64+dh]: lane has l fixed (w*16+l15), dh = nt*16+quad*4+r -> 8B packed
    int b = bh / H_, h = bh % H_;
    long l = qt * 128 + w * 16 + l15;
#pragma unroll
    for (int nt = 0; nt < 4; nt++)
        pack4_store(&Ctx[(long)(b * L_ + l) * D_ + h * DH_ + nt * 16 + quad * 4],
                    O[nt][0] * rcp, O[nt][1] * rcp, O[nt][2] * rcp, O[nt][3] * rcp);
}

extern "C" void kernel_launch(void* const* d_in, const int* in_sizes, int n_in,
                              void* d_out, int out_size, void* d_ws, size_t ws_size,
                              hipStream_t stream) {
    const float* X   = (const float*)d_in[0];
    const float* Wq  = (const float*)d_in[1];
    const float* Wk  = (const float*)d_in[2];
    const float* Wv  = (const float*)d_in[3];
    const float* Wo  = (const float*)d_in[4];
    const float* bo  = (const float*)d_in[5];
    const float* Kbg = (const float*)d_in[6];
    const float* Vbg = (const float*)d_in[7];

    char* ws = (char*)d_ws;
    size_t off = 0;
    auto alloc = [&](size_t bytes) {
        void* p = ws + off;
        off = (off + bytes + 255) & ~(size_t)255;
        return p;
    };
    ushort* Wt    = (ushort*)alloc((size_t)4 * D_ * D_ * 2);     // Wq^T|Wk^T|Wv^T|Wo^T
    ushort* Qp    = (ushort*)alloc((size_t)BH_ * L_ * DH_ * 2);
    ushort* Kp    = (ushort*)alloc((size_t)BH_ * L_ * DH_ * 2);
    ushort* Kcv   = (ushort*)alloc((size_t)BH_ * L_ * DH_ * 2);  // bf16(Kbg)
    ushort* Vt    = (ushort*)alloc((size_t)BH_ * DH_ * L2_ * 2); // [V^T ; alpha V_bg^T]
    ushort* Xb    = (ushort*)alloc((size_t)B_ * L_ * D_ * 2);    // bf16(X); Ctx aliases
    ushort* Ctx   = Xb;  // Xb dead after QKV GEMM; flash writes Ctx afterwards
    ushort* Wqkv_t = Wt;
    ushort* Wo_t   = Wt + (size_t)3 * D_ * D_;

    prep<<<8000, 256, 0, stream>>>(Wq, Wk, Wv, Wo, Wt, Vbg, Vt, X, Xb, Kbg, Kcv);
    // QKV projection: N = 3840 (Q|K|V), M = 4096 (R7 config: 128x128, 960 blocks)
    gemm_tpl<128, 128, 2, 2><<<dim3(30, 32), 256, 0, stream>>>(
        Xb, Wqkv_t, Qp, Kp, Vt, nullptr, nullptr, 0);
    // attention: 640 blocks x 512 threads, XCD-swizzled, stage-together dbuf
    flash_attn<<<dim3(640), 512, 0, stream>>>(Qp, Kp, Kcv, Vt, Ctx);
    // output projection (R7 config: 64x128, 640 blocks)
    gemm_tpl<64, 128, 1, 4><<<dim3(10, 64), 256, 0, stream>>>(
        Ctx, Wo_t, nullptr, nullptr, nullptr, (float*)d_out, bo, 1);
}